// Round 8
// baseline (54.769 us; speedup 1.0000x reference)
//
#include <hip/hip_runtime.h>
#include <math.h>

// Problem constants (from reference setup_inputs)
#define BATCH 64
#define NPATCH 784
#define DIM 768
#define KSEL 392          // int(784 * 0.5)
#define SIDE 28
#define HWDIM 448
#define NPIX (HWDIM*HWDIM)     // 200704
#define PARTS 28               // blocks per batch for COG partial reduction
#define PIX_PER_PART (NPIX/PARTS)  // 7168 (16 full rows)
#define F4_PER_THREAD 7        // 7168 / 4 / 256
#define GSPLIT 8               // selection blocks per batch
#define IPB 98                 // elements ranked per selection block (784/8)

typedef float f4v __attribute__((ext_vector_type(4)));
typedef unsigned long long u64;

// ---------------------------------------------------------------------------
// Kernel 1: partial COG sums per (batch, part). Per-element f32 products
// emulate numpy rounding; f64 accumulation in a fixed deterministic order
// (serial per thread, then wave shuffle butterfly, then 4-way serial).
// All f64 divisions hoisted into a 448-entry LDS linspace table; PARTS=28
// halves the number of blocks paying that fixed cost vs PARTS=49.
// ---------------------------------------------------------------------------
__global__ __launch_bounds__(256) void cog_partial(const float* __restrict__ ld,
                                                   double* __restrict__ part) {
    const int blk = blockIdx.x;
    const int b = blk / PARTS;
    const int p = blk % PARTS;
    const int t = threadIdx.x;
    const int wid = t >> 6;
    const int lane = t & 63;

    __shared__ alignas(16) float lin[HWDIM];   // f32(e/447.0) == np.linspace(0,1,448)
    for (int e = t; e < HWDIM; e += 256) lin[e] = (float)((double)e / 447.0);
    __syncthreads();

    const float* base = ld + (size_t)b * NPIX + (size_t)p * PIX_PER_PART;
    double s = 0.0, sy = 0.0, sx = 0.0;

    // 7168 pixels per part = 1792 float4; 256 threads x 7 float4 each.
    // 448 % 4 == 0 so each float4 stays within one image row, and j % 4 == 0
    // so the x-coordinate quad is one aligned LDS float4 read.
    #pragma unroll
    for (int r = 0; r < F4_PER_THREAD; ++r) {
        const int f4 = r * 256 + t;                 // 0..1791
        const int pix = p * PIX_PER_PART + f4 * 4;  // within-batch pixel idx
        const f4v v = reinterpret_cast<const f4v*>(base)[f4];
        const int i = pix / HWDIM;
        const int j = pix - i * HWDIM;
        const float yf = lin[i];
        const f4v xq = *reinterpret_cast<const f4v*>(&lin[j]);
        s  += (double)v.x + (double)v.y + (double)v.z + (double)v.w;
        sy += (double)__fmul_rn(v.x, yf) + (double)__fmul_rn(v.y, yf)
            + (double)__fmul_rn(v.z, yf) + (double)__fmul_rn(v.w, yf);
        sx += (double)__fmul_rn(v.x, xq.x) + (double)__fmul_rn(v.y, xq.y)
            + (double)__fmul_rn(v.z, xq.z) + (double)__fmul_rn(v.w, xq.w);
    }

    // in-wave butterfly reduce (fixed order -> deterministic)
    #pragma unroll
    for (int off = 32; off > 0; off >>= 1) {
        s  += __shfl_down(s, off);
        sy += __shfl_down(sy, off);
        sx += __shfl_down(sx, off);
    }

    __shared__ double red[3][4];
    if (lane == 0) { red[0][wid] = s; red[1][wid] = sy; red[2][wid] = sx; }
    __syncthreads();
    if (t == 0) {
        double* dst = part + (size_t)(b * PARTS + p) * 3;
        dst[0] = (red[0][0] + red[0][1]) + (red[0][2] + red[0][3]);
        dst[1] = (red[1][0] + red[1][1]) + (red[1][2] + red[1][3]);
        dst[2] = (red[2][0] + red[2][1]) + (red[2][2] + red[2][3]);
    }
}

// ---------------------------------------------------------------------------
// Kernel 2: fused COG-combine + selection via packed 64-bit sort keys.
//   key(n) = (bits(w_n) << 10) | (1023 - n)   (w_n >= 0, so bit order == value
//   order; low bits break ties exactly like lax.top_k: lower index ranks first)
// Facts used (proven from the reference semantics):
//   - r_all = #{j: key_j > key_i} is the stable descending-top-k slot.
//   - In the combined (0 < count < k) path, a BELOW-threshold element's slot
//     count + r_below == r_all (every above-threshold j outranks every
//     below-threshold i, strictly).
//   - An ABOVE-threshold element's slot is r_pre = #{above j < i}: a prefix
//     popcount over the 784-bit above-mask (built with wave ballots).
// GSPLIT=8 (512 blocks, 2/CU) spreads the LDS-BW-bound rank loop across
// twice the CU LDS pipes; the cheap key build is duplicated per block.
// ---------------------------------------------------------------------------
__global__ __launch_bounds__(256) void select_k(const float* __restrict__ scores,
                                                const double* __restrict__ part,
                                                int* __restrict__ sel) {
    const int blk = blockIdx.x;
    const int b = blk / GSPLIT;
    const int g = blk % GSPLIT;
    const int t = threadIdx.x;
    const int wid = t >> 6;
    const int lane = t & 63;

    __shared__ double sd[3][64];
    __shared__ float scog[2];
    __shared__ alignas(16) u64 skey[NPATCH];
    __shared__ u64 ajm[16];                 // 784-bit above-threshold mask (padded)

    // --- COG combine (deterministic fixed-order tree over 28 partials;
    //     identical code+data in all 8 blocks of a batch) ---
    if (t < 64) {
        if (t < PARTS) {
            const double* src = part + (size_t)(b * PARTS + t) * 3;
            sd[0][t] = src[0]; sd[1][t] = src[1]; sd[2][t] = src[2];
        } else {
            sd[0][t] = 0.0; sd[1][t] = 0.0; sd[2][t] = 0.0;
        }
    }
    __syncthreads();
    for (int off = 32; off > 0; off >>= 1) {
        if (t < off) {
            sd[0][t] += sd[0][t + off];
            sd[1][t] += sd[1][t + off];
            sd[2][t] += sd[2][t + off];
        }
        __syncthreads();
    }
    if (t == 0) {
        // reference: total = sum + 1e-6 (f32); cog = num / total (f32)
        const float total = __fadd_rn((float)sd[0][0], 1e-6f);
        scog[0] = __fdiv_rn((float)sd[1][0], total);   // cy
        scog[1] = __fdiv_rn((float)sd[2][0], total);   // cx
    }
    __syncthreads();
    const float cy = scog[0];
    const float cx = scog[1];

    // --- weighted scores -> keys + ballot above-mask ---
    #pragma unroll
    for (int pass = 0; pass < 4; ++pass) {
        const int n = pass * 256 + t;
        const bool valid = n < NPATCH;
        float wt = 0.0f;
        if (valid) {
            const int r = n / SIDE;
            const int c = n - r * SIDE;
            // linspace(0,1,28)[i] = f32(i/27)
            const float gy = (float)((double)r / 27.0);
            const float gx = (float)((double)c / 27.0);
            const float dy = gy - cy;
            const float dx = gx - cx;
            // numpy: dy2, dx2 rounded separately, then summed (no FMA)
            const float dy2 = __fmul_rn(dy, dy);
            const float dx2 = __fmul_rn(dx, dx);
            const float d2 = __fadd_rn(dy2, dx2);
            // -d2/0.125 == -8*d2 exactly; exp in f64 then round (<=0.5 ulp)
            const float w = (float)exp((double)(-8.0f * d2));
            wt = __fmul_rn(scores[(size_t)b * NPATCH + n], w);
            skey[n] = ((u64)__float_as_uint(wt) << 10) | (u64)(1023 - n);
        }
        const u64 m = __ballot(valid && (wt > 0.3f));
        if (lane == 0) ajm[pass * 4 + wid] = m;     // bits for n in [64q, 64q+64)
    }
    __syncthreads();

    // --- rank my element ---
    const int i = g * IPB + t;
    if (t < IPB) {
        const u64 ki = skey[i];
        int r0 = 0, r1 = 0, r2 = 0, r3 = 0;
        #pragma unroll 4
        for (int j = 0; j < NPATCH; j += 4) {
            r0 += skey[j + 0] > ki;
            r1 += skey[j + 1] > ki;
            r2 += skey[j + 2] > ki;
            r3 += skey[j + 3] > ki;
        }
        const int r_all = (r0 + r1) + (r2 + r3);

        int count = 0;
        #pragma unroll
        for (int q = 0; q < 16; ++q) count += __popcll(ajm[q]);

        const int qi = i >> 6;
        const bool above_i = (ajm[qi] >> (u64)(i & 63)) & 1ull;
        int r_pre = 0;
        for (int q = 0; q < qi; ++q) r_pre += __popcll(ajm[q]);
        r_pre += __popcll(ajm[qi] & ((1ull << (u64)(i & 63)) - 1ull));

        const bool use_topk = (count == 0) || (count >= KSEL);
        const int dst = (!use_topk && above_i) ? r_pre : r_all;
        if (dst < KSEL) sel[(size_t)b * KSEL + dst] = i;
    }
}

// ---------------------------------------------------------------------------
// Kernel 3: gather + add. 256 threads = 4 waves; TWO rows per wave with all
// 12 loads issued before the adds (MLP), 3 float4 per lane per row. Cached
// loads (pos stays L2-resident); nontemporal stores for the write-once output.
// ---------------------------------------------------------------------------
__global__ __launch_bounds__(256) void gather_add(const float* __restrict__ magno,
                                                  const float* __restrict__ pos,
                                                  const int* __restrict__ sel,
                                                  float* __restrict__ out) {
    const int wid = threadIdx.x >> 6;
    const int lane = threadIdx.x & 63;
    const int w = blockIdx.x * 4 + wid;     // wave id: 0 .. BATCH*KSEL/2 - 1
    const int row0 = w * 2;
    const int row1 = row0 + 1;
    const int b0 = row0 / KSEL;
    const int b1 = row1 / KSEL;
    const int s0 = sel[row0];
    const int s1 = sel[row1];

    const f4v* src0 = reinterpret_cast<const f4v*>(magno + ((size_t)b0 * NPATCH + s0) * DIM);
    const f4v* src1 = reinterpret_cast<const f4v*>(magno + ((size_t)b1 * NPATCH + s1) * DIM);
    const f4v* pp0  = reinterpret_cast<const f4v*>(pos + (size_t)(s0 + 1) * DIM);
    const f4v* pp1  = reinterpret_cast<const f4v*>(pos + (size_t)(s1 + 1) * DIM);
    f4v* dst0 = reinterpret_cast<f4v*>(out + (size_t)row0 * DIM);
    f4v* dst1 = reinterpret_cast<f4v*>(out + (size_t)row1 * DIM);

    const f4v a0 = src0[lane], a1 = src0[64 + lane], a2 = src0[128 + lane];
    const f4v c0 = src1[lane], c1 = src1[64 + lane], c2 = src1[128 + lane];
    const f4v p0 = pp0[lane],  p1 = pp0[64 + lane],  p2 = pp0[128 + lane];
    const f4v q0 = pp1[lane],  q1 = pp1[64 + lane],  q2 = pp1[128 + lane];

    __builtin_nontemporal_store(a0 + p0, dst0 + lane);
    __builtin_nontemporal_store(a1 + p1, dst0 + 64 + lane);
    __builtin_nontemporal_store(a2 + p2, dst0 + 128 + lane);
    __builtin_nontemporal_store(c0 + q0, dst1 + lane);
    __builtin_nontemporal_store(c1 + q1, dst1 + 64 + lane);
    __builtin_nontemporal_store(c2 + q2, dst1 + 128 + lane);
}

extern "C" void kernel_launch(void* const* d_in, const int* in_sizes, int n_in,
                              void* d_out, int out_size, void* d_ws, size_t ws_size,
                              hipStream_t stream) {
    const float* magno  = (const float*)d_in[0];  // [64, 784, 768]
    const float* vit    = (const float*)d_in[1];  // [1, 785, 768]
    const float* scores = (const float*)d_in[2];  // [64, 784]
    const float* ld     = (const float*)d_in[3];  // [64, 1, 448, 448]
    float* out = (float*)d_out;                   // [64, 392, 768]

    // workspace layout
    double* partials = (double*)d_ws;             // 64*28*3 doubles
    int*    sel = (int*)((char*)d_ws + (size_t)BATCH * PARTS * 3 * sizeof(double));

    cog_partial<<<dim3(BATCH * PARTS), dim3(256), 0, stream>>>(ld, partials);
    select_k<<<dim3(BATCH * GSPLIT), dim3(256), 0, stream>>>(scores, partials, sel);
    gather_add<<<dim3(BATCH * KSEL / 8), dim3(256), 0, stream>>>(magno, vit, sel, out);
}

// Round 9
// 47.346 us; speedup vs baseline: 1.1568x; 1.1568x over previous
//
#include <hip/hip_runtime.h>
#include <math.h>

// Problem constants (from reference setup_inputs)
#define BATCH 64
#define NPATCH 784
#define DIM 768
#define KSEL 392          // int(784 * 0.5)
#define SIDE 28
#define HWDIM 448
#define NPIX (HWDIM*HWDIM)     // 200704
#define PARTS 49               // blocks per batch for COG partial reduction (R7-proven)
#define PIX_PER_PART (NPIX/PARTS)  // 4096
#define GSPLIT 16              // fused select+gather blocks per batch
#define IPB 49                 // source elements per fused block (784/16)

typedef float f4v __attribute__((ext_vector_type(4)));
typedef unsigned long long u64;

// ---------------------------------------------------------------------------
// Kernel 1: partial COG sums per (batch, part) — identical to R7 (best
// measured). f32 per-element products emulate numpy rounding; f64 fixed-order
// accumulation (serial per thread, wave shuffle butterfly, 4-way serial).
// ---------------------------------------------------------------------------
__global__ __launch_bounds__(256) void cog_partial(const float* __restrict__ ld,
                                                   double* __restrict__ part) {
    const int blk = blockIdx.x;
    const int b = blk / PARTS;
    const int p = blk % PARTS;
    const int t = threadIdx.x;
    const int wid = t >> 6;
    const int lane = t & 63;

    __shared__ alignas(16) float lin[HWDIM];   // f32(e/447.0) == np.linspace(0,1,448)
    for (int e = t; e < HWDIM; e += 256) lin[e] = (float)((double)e / 447.0);
    __syncthreads();

    const float* base = ld + (size_t)b * NPIX + (size_t)p * PIX_PER_PART;
    double s = 0.0, sy = 0.0, sx = 0.0;

    // 4096 pixels per part = 1024 float4; 256 threads x 4 float4 each.
    #pragma unroll
    for (int r = 0; r < 4; ++r) {
        const int f4 = r * 256 + t;                 // 0..1023
        const int pix = p * PIX_PER_PART + f4 * 4;  // within-batch pixel idx
        const f4v v = reinterpret_cast<const f4v*>(base)[f4];
        const int i = pix / HWDIM;
        const int j = pix - i * HWDIM;              // j % 4 == 0
        const float yf = lin[i];
        const f4v xq = *reinterpret_cast<const f4v*>(&lin[j]);
        s  += (double)v.x + (double)v.y + (double)v.z + (double)v.w;
        sy += (double)__fmul_rn(v.x, yf) + (double)__fmul_rn(v.y, yf)
            + (double)__fmul_rn(v.z, yf) + (double)__fmul_rn(v.w, yf);
        sx += (double)__fmul_rn(v.x, xq.x) + (double)__fmul_rn(v.y, xq.y)
            + (double)__fmul_rn(v.z, xq.z) + (double)__fmul_rn(v.w, xq.w);
    }

    #pragma unroll
    for (int off = 32; off > 0; off >>= 1) {
        s  += __shfl_down(s, off);
        sy += __shfl_down(sy, off);
        sx += __shfl_down(sx, off);
    }

    __shared__ double red[3][4];
    if (lane == 0) { red[0][wid] = s; red[1][wid] = sy; red[2][wid] = sx; }
    __syncthreads();
    if (t == 0) {
        double* dst = part + (size_t)(b * PARTS + p) * 3;
        dst[0] = (red[0][0] + red[0][1]) + (red[0][2] + red[0][3]);
        dst[1] = (red[1][0] + red[1][1]) + (red[1][2] + red[1][3]);
        dst[2] = (red[2][0] + red[2][1]) + (red[2][2] + red[2][3]);
    }
}

// ---------------------------------------------------------------------------
// Kernel 2: fused selection + gather. Block (b,g) rebuilds batch b's keys
// (deterministic, identical across the 16 blocks of a batch), ranks its 49
// source elements, and copies the selected rows directly. No cross-block
// ordering: every block computes everything it consumes.
//   key(n) = (bits(w_n) << 10) | (1023 - n): w_n >= 0 so bit order == value
//   order; low bits reproduce lax.top_k's lower-index-first tie-break.
//   Slots are a bijection onto [0, KSEL): top-k path -> distinct r_all<KSEL;
//   combined path -> above fills [0,count) via r_pre, below fills
//   [count,KSEL) via r_all (== count + r_below, proven).
// ---------------------------------------------------------------------------
__global__ __launch_bounds__(256) void select_gather(
        const float* __restrict__ scores,  // [64, 784]
        const double* __restrict__ part,   // [64*49*3]
        const float* __restrict__ magno,   // [64, 784, 768]
        const float* __restrict__ pos,     // [1, 785, 768]
        float* __restrict__ out) {         // [64, 392, 768]
    const int blk = blockIdx.x;
    const int b = blk / GSPLIT;
    const int g = blk % GSPLIT;
    const int t = threadIdx.x;
    const int wid = t >> 6;
    const int lane = t & 63;

    __shared__ double sd[3][64];
    __shared__ float scog[2];
    __shared__ alignas(16) u64 skey[NPATCH];
    __shared__ u64 ajm[16];                 // 784-bit above-threshold mask
    __shared__ int sred[IPB * 4];           // 4-way rank partials
    __shared__ unsigned spair[IPB];         // packed (src<<16)|dst
    __shared__ int snsel;

    // --- COG combine (deterministic fixed-order tree over 49 partials) ---
    if (t < 64) {
        if (t < PARTS) {
            const double* src = part + (size_t)(b * PARTS + t) * 3;
            sd[0][t] = src[0]; sd[1][t] = src[1]; sd[2][t] = src[2];
        } else {
            sd[0][t] = 0.0; sd[1][t] = 0.0; sd[2][t] = 0.0;
        }
    }
    __syncthreads();
    for (int off = 32; off > 0; off >>= 1) {
        if (t < off) {
            sd[0][t] += sd[0][t + off];
            sd[1][t] += sd[1][t + off];
            sd[2][t] += sd[2][t + off];
        }
        __syncthreads();
    }
    if (t == 0) {
        // reference: total = sum + 1e-6 (f32); cog = num / total (f32)
        const float total = __fadd_rn((float)sd[0][0], 1e-6f);
        scog[0] = __fdiv_rn((float)sd[1][0], total);   // cy
        scog[1] = __fdiv_rn((float)sd[2][0], total);   // cx
    }
    __syncthreads();
    const float cy = scog[0];
    const float cx = scog[1];

    // --- weighted scores -> keys + ballot above-mask ---
    #pragma unroll
    for (int pass = 0; pass < 4; ++pass) {
        const int n = pass * 256 + t;
        const bool valid = n < NPATCH;
        float wt = 0.0f;
        if (valid) {
            const int r = n / SIDE;
            const int c = n - r * SIDE;
            // linspace(0,1,28)[i] = f32(i/27)
            const float gy = (float)((double)r / 27.0);
            const float gx = (float)((double)c / 27.0);
            const float dy = gy - cy;
            const float dx = gx - cx;
            // numpy: dy2, dx2 rounded separately, then summed (no FMA)
            const float dy2 = __fmul_rn(dy, dy);
            const float dx2 = __fmul_rn(dx, dx);
            const float d2 = __fadd_rn(dy2, dx2);
            // -d2/0.125 == -8*d2 exactly; exp in f64 then round (<=0.5 ulp)
            const float w = (float)exp((double)(-8.0f * d2));
            wt = __fmul_rn(scores[(size_t)b * NPATCH + n], w);
            skey[n] = ((u64)__float_as_uint(wt) << 10) | (u64)(1023 - n);
        }
        const u64 m = __ballot(valid && (wt > 0.3f));
        if (lane == 0) ajm[pass * 4 + wid] = m;     // bits for n in [64q, 64q+64)
    }
    __syncthreads();

    // --- rank partials: thread (e,q) covers j in [q*196, (q+1)*196) ---
    if (t < IPB * 4) {
        const int e = t >> 2;
        const int q = t & 3;
        const u64 ki = skey[g * IPB + e];
        const int j0 = q * 196;
        int r0 = 0, r1 = 0, r2 = 0, r3 = 0;
        #pragma unroll 4
        for (int j = j0; j < j0 + 196; j += 4) {
            r0 += skey[j + 0] > ki;
            r1 += skey[j + 1] > ki;
            r2 += skey[j + 2] > ki;
            r3 += skey[j + 3] > ki;
        }
        sred[t] = (r0 + r1) + (r2 + r3);
    }
    __syncthreads();

    // --- finish rank, compute slot, ballot-compact pairs (wave 0 only) ---
    if (t < 64) {
        int mydst = KSEL;      // not selected
        int mysrc = 0;
        if (t < IPB) {
            const int i = g * IPB + t;
            const int r_all = (sred[t * 4] + sred[t * 4 + 1])
                            + (sred[t * 4 + 2] + sred[t * 4 + 3]);

            int count = 0;
            #pragma unroll
            for (int q = 0; q < 16; ++q) count += __popcll(ajm[q]);

            const int qi = i >> 6;
            const bool above_i = (ajm[qi] >> (u64)(i & 63)) & 1ull;
            int r_pre = 0;
            for (int q = 0; q < qi; ++q) r_pre += __popcll(ajm[q]);
            r_pre += __popcll(ajm[qi] & ((1ull << (u64)(i & 63)) - 1ull));

            const bool use_topk = (count == 0) || (count >= KSEL);
            mydst = (!use_topk && above_i) ? r_pre : r_all;
            mysrc = i;
        }
        const bool selme = mydst < KSEL;
        const u64 mask = __ballot(selme);
        if (selme) {
            const int posi = __popcll(mask & ((1ull << (u64)t) - 1ull));
            spair[posi] = ((unsigned)mysrc << 16) | (unsigned)mydst;
        }
        if (t == 0) snsel = (int)__popcll(mask);
    }
    __syncthreads();

    // --- copy selected rows: one row per wave per iteration ---
    const int nsel = snsel;
    for (int e = wid; e < nsel; e += 4) {
        const unsigned pr = spair[e];
        const int srcn = (int)(pr >> 16);
        const int dslot = (int)(pr & 0xffffu);
        const f4v* src = reinterpret_cast<const f4v*>(magno + ((size_t)b * NPATCH + srcn) * DIM);
        const f4v* pp  = reinterpret_cast<const f4v*>(pos + (size_t)(srcn + 1) * DIM);
        f4v* dq = reinterpret_cast<f4v*>(out + ((size_t)b * KSEL + dslot) * DIM);
        const f4v a0 = src[lane], a1 = src[64 + lane], a2 = src[128 + lane];
        const f4v p0 = pp[lane],  p1 = pp[64 + lane],  p2 = pp[128 + lane];
        __builtin_nontemporal_store(a0 + p0, dq + lane);
        __builtin_nontemporal_store(a1 + p1, dq + 64 + lane);
        __builtin_nontemporal_store(a2 + p2, dq + 128 + lane);
    }
}

extern "C" void kernel_launch(void* const* d_in, const int* in_sizes, int n_in,
                              void* d_out, int out_size, void* d_ws, size_t ws_size,
                              hipStream_t stream) {
    const float* magno  = (const float*)d_in[0];  // [64, 784, 768]
    const float* vit    = (const float*)d_in[1];  // [1, 785, 768]
    const float* scores = (const float*)d_in[2];  // [64, 784]
    const float* ld     = (const float*)d_in[3];  // [64, 1, 448, 448]
    float* out = (float*)d_out;                   // [64, 392, 768]

    // workspace layout
    double* partials = (double*)d_ws;             // 64*49*3 doubles

    cog_partial<<<dim3(BATCH * PARTS), dim3(256), 0, stream>>>(ld, partials);
    select_gather<<<dim3(BATCH * GSPLIT), dim3(256), 0, stream>>>(scores, partials,
                                                                  magno, vit, out);
}